// Round 1
// 293.158 us; speedup vs baseline: 1.1041x; 1.1041x over previous
//
#include <hip/hip_runtime.h>

#define NN 100000
#define NE 3200000
#define HID 64
#define NPB 256                         // nodes per bucket (dl = dst & 255, 8 bits)
#define NB  ((NN + NPB - 1) / NPB)      // 391 buckets
#define CAP 9216                        // fixed bucket capacity: mean 8192, +11 sigma
#define MNP 128                         // nodes per k_mega window
#define NMW ((NN + MNP - 1) / MNP)      // 782 mega windows
#define CHUNK 4096                      // edges per scatter workgroup
#define NCH ((NE + CHUNK - 1) / CHUNK)  // 782 chunks
#define AP 72                           // f16 agg row pitch in halfs (144 B, 16B-aligned)
#define BPITCH 136                      // f16 Bt row pitch in halfs (272 B)
#define SRCM 0x1FFFF                    // src mask (17 bits; NN < 2^17)

typedef _Float16 half8 __attribute__((ext_vector_type(8)));
typedef _Float16 h2v   __attribute__((ext_vector_type(2)));
typedef float f32x4 __attribute__((ext_vector_type(4)));

__device__ __forceinline__ float h2f(unsigned int u) {
    unsigned short s = (unsigned short)u;
    _Float16 h;
    __builtin_memcpy(&h, &s, 2);
    return (float)h;
}
__device__ __forceinline__ unsigned short f2hb(float v) {
    _Float16 h = (_Float16)v;
    unsigned short s;
    __builtin_memcpy(&s, &h, 2);
    return s;
}
__device__ __forceinline__ h2v ash2(unsigned int u) {
    h2v r;
    __builtin_memcpy(&r, &u, 4);
    return r;
}

// -------- init fixed-capacity bucket cursors (replaces hist+scan+memset) --------
__global__ __launch_bounds__(512) void k_init(int* __restrict__ gcur) {
    const int t = threadIdx.x;
    if (t < NB) gcur[t] = t * CAP;
}

// -------- scatter with in-LDS counting sort -> bucket-grouped coalesced emission ----
__global__ __launch_bounds__(256) void k_scatter(const int* __restrict__ src,
                                                 const int* __restrict__ dst,
                                                 const float* __restrict__ ew,
                                                 int* __restrict__ gcur,
                                                 int2* __restrict__ rec) {
    __shared__ int2 lrec[CHUNK];              // 32 KB
    __shared__ unsigned short lb[CHUNK];      // 8 KB  (bucket id per record)
    __shared__ unsigned short sidx[CHUNK];    // 8 KB  (sorted-order -> record idx)
    __shared__ int cnt[NB];                   // counts, then reused as cursor
    __shared__ int excl[NB];
    __shared__ int base[NB];
    __shared__ int sc[512];
    const int tid = threadIdx.x;
    for (int j = tid; j < NB; j += 256) cnt[j] = 0;
    __syncthreads();
    const long long b0 = (long long)blockIdx.x * CHUNK;
    const int valid = (int)min((long long)CHUNK, (long long)NE - b0);
    #pragma unroll
    for (int k = 0; k < CHUNK / 256; ++k) {
        int idx = k * 256 + tid;
        if (idx < valid) {
            long long e = b0 + idx;
            int d = dst[e];
            int b = d >> 8;
            lrec[idx] = make_int2(src[e] | ((d & 255) << 17), __float_as_int(ew[e]));
            lb[idx] = (unsigned short)b;
            atomicAdd(&cnt[b], 1);
        }
    }
    __syncthreads();
    // inclusive scan of counts (512-slot Hillis-Steele, NB=391 padded)
    {
        int v = (tid < NB) ? cnt[tid] : 0;
        sc[tid] = v;
        int v2 = (tid + 256 < NB) ? cnt[tid + 256] : 0;
        sc[tid + 256] = v2;
        __syncthreads();
        #pragma unroll
        for (int off = 1; off < 512; off <<= 1) {
            int a0 = (tid >= off) ? sc[tid - off] : 0;
            int a1 = (tid + 256 >= off) ? sc[tid + 256 - off] : 0;
            __syncthreads();
            sc[tid] += a0;
            sc[tid + 256] += a1;
            __syncthreads();
        }
        if (tid < NB) excl[tid] = sc[tid] - cnt[tid];
        if (tid + 256 < NB) excl[tid + 256] = sc[tid + 256] - cnt[tid + 256];
    }
    __syncthreads();
    // global reservation + init cursor to local exclusive offset
    for (int j = tid; j < NB; j += 256) {
        int c = cnt[j];
        base[j] = c ? atomicAdd(&gcur[j], c) : 0;
        cnt[j] = excl[j];                     // cursor
    }
    __syncthreads();
    // placement: sorted position per record
    #pragma unroll
    for (int k = 0; k < CHUNK / 256; ++k) {
        int idx = k * 256 + tid;
        if (idx < valid) {
            int sp = atomicAdd(&cnt[lb[idx]], 1);
            sidx[sp] = (unsigned short)idx;
        }
    }
    __syncthreads();
    // emission in bucket order: consecutive lanes -> consecutive addresses per run
    #pragma unroll
    for (int k = 0; k < CHUNK / 256; ++k) {
        int sp = k * 256 + tid;
        if (sp < valid) {
            int idx = sidx[sp];
            int b = lb[idx];
            rec[base[b] + (sp - excl[b])] = lrec[idx];
        }
    }
}

// -------- bucketed s1: sx[i] = (s1[i], x[i]) --------
__global__ __launch_bounds__(512) void k_s1(const int* __restrict__ gcur,
                                            const int2* __restrict__ rec,
                                            const float* __restrict__ x,
                                            float2* __restrict__ sx) {
    __shared__ float loc[NPB];
    if (threadIdx.x < NPB) loc[threadIdx.x] = 0.f;
    __syncthreads();
    const int b = blockIdx.x;
    const int beg = b * CAP, cnt = gcur[b] - beg;
    for (int t = threadIdx.x; t < cnt; t += 512) {
        int2 rc = rec[beg + t];
        atomicAdd(&loc[rc.x >> 17], __int_as_float(rc.y) * x[rc.x & SRCM]);
    }
    __syncthreads();
    int i = b * NPB + threadIdx.x;
    if (threadIdx.x < NPB && i < NN) sx[i] = make_float2(loc[threadIdx.x], x[i]);
}

// -------- sort2: dl-hist + scan + direct packed rec2 emit (fused prep) --------
__global__ __launch_bounds__(512) void k_sort2(const int* __restrict__ gcur,
                                               const int2* __restrict__ rec,
                                               const float2* __restrict__ sx,
                                               int2* __restrict__ rec2,
                                               int* __restrict__ nbase,
                                               int* __restrict__ nend) {
    __shared__ int hist[NPB];
    __shared__ int excl[NPB];
    __shared__ int cur[NPB];
    const int tid = threadIdx.x;
    if (tid < NPB) hist[tid] = 0;
    __syncthreads();
    const int b = blockIdx.x;
    const int beg = b * CAP, cnt = gcur[b] - beg;
    for (int t = tid; t < cnt; t += 512)
        atomicAdd(&hist[rec[beg + t].x >> 17], 1);
    __syncthreads();
    if (tid < NPB) excl[tid] = hist[tid];
    __syncthreads();
    #pragma unroll
    for (int off = 1; off < NPB; off <<= 1) {
        int t = (tid < NPB && tid >= off) ? excl[tid - off] : 0;
        __syncthreads();
        if (tid < NPB) excl[tid] += t;
        __syncthreads();
    }
    if (tid < NPB) {
        int e0 = excl[tid] - hist[tid];
        cur[tid] = e0;
        int i = b * NPB + tid;
        if (i < NN) {
            nbase[i] = beg + e0;
            nend[i]  = beg + e0 + hist[tid];
        }
    }
    __syncthreads();
    for (int t = tid; t < cnt; t += 512) {
        int2 rc = rec[beg + t];                 // L2-hot re-read
        const int s = rc.x & SRCM;
        const int dl = rc.x >> 17;
        const float w = __int_as_float(rc.y);
        const float2 v = sx[s];                 // per-lane gather, L2-resident
        int pos = atomicAdd(&cur[dl], 1);
        rec2[beg + pos] = make_int2((int)f2hb(w * v.x) | ((int)f2hb(w * v.y) << 16),
                                    (int)f2hb(w) | (dl << 16));
    }
}

// -------- mega: 128-node windows, paired pk-f16 streaming + MFMA --------
__global__ __launch_bounds__(512) void k_mega(
        const int* __restrict__ nbase, const int* __restrict__ nend,
        const int2* __restrict__ rec2, const float2* __restrict__ sx,
        const float* __restrict__ W1_rel, const float* __restrict__ W1_root,
        const float* __restrict__ b1,
        const float* __restrict__ W2_rel, const float* __restrict__ b2,
        const float* __restrict__ W2_root,
        const float* __restrict__ W3_rel, const float* __restrict__ W3_root,
        float* __restrict__ p, float* __restrict__ r) {
    __shared__ _Float16 aggh[MNP * AP];       // 18432 B
    __shared__ _Float16 Bt[HID * BPITCH];     // 17408 B
    __shared__ float2 sxl[MNP];               // 1024 B -> 36.9 KB
    const int tid = threadIdx.x;
    const int f = tid & 63;
    const int wv = tid >> 6;                  // 0..7
    const int gi0 = blockIdx.x * MNP;

    for (int j = tid; j < MNP * AP / 2; j += 512) ((int*)aggh)[j] = 0;
    for (int idx = tid; idx < HID * HID; idx += 512) {
        int k = idx >> 6, n = idx & 63;
        Bt[n * BPITCH + k]       = (_Float16)W2_rel[idx];
        Bt[n * BPITCH + HID + k] = (_Float16)W2_root[idx];
    }
    if (tid < MNP) {
        int gi = gi0 + tid;
        sxl[tid] = (gi < NN) ? sx[gi] : make_float2(0.f, 0.f);
    }
    const float w1r = W1_rel[f], w1t = W1_root[f], b1f = b1[f];
    __syncthreads();

    {
        const int first = gi0 + wv * 16;
        int e = 0, eend = 0;
        if (first < NN) {
            e = nbase[first];
            eend = nend[min(first + 15, NN - 1)];
        }
        // wave-uniform stream cursors: let the compiler use scalar loads
        e = __builtin_amdgcn_readfirstlane(e);
        eend = __builtin_amdgcn_readfirstlane(eend);
        int curn = -1;
        float a0 = 0.f, a1 = 0.f, a2 = 0.f, a3 = 0.f;
        const h2v w1r2 = {(_Float16)w1r, (_Float16)w1r};
        const h2v w1t2 = {(_Float16)w1t, (_Float16)w1t};
        const h2v b1f2 = {(_Float16)b1f, (_Float16)b1f};
        const h2v one2 = {(_Float16)1.f, (_Float16)1.f};
        const h2v zero2 = {(_Float16)0.f, (_Float16)0.f};

#define FLUSHA() { if (curn >= 0) aggh[(curn & 127) * AP + f] = (_Float16)((a0 + a1) + (a2 + a3)); }

// scalar fallback path (f32), handles node-boundary flush
#define SPROC(X, Y, AA)                                                           \
        {                                                                         \
            const int dl_ = ((unsigned)(Y)) >> 16;                                \
            if (dl_ != curn) {                                                    \
                FLUSHA();                                                         \
                curn = dl_; a0 = a1 = a2 = a3 = 0.f;                              \
            }                                                                     \
            const float ws_ = h2f((unsigned)(X) & 0xFFFF);                        \
            const float wx_ = h2f(((unsigned)(X)) >> 16);                         \
            const float wf_ = h2f((unsigned)(Y) & 0xFFFF);                        \
            AA += fmaxf(0.f, fmaf(ws_, w1r, fmaf(wx_, w1t, wf_ * b1f)));          \
        }

// paired fast path: 2 edges, 3 perms + 3 pk f16 ops + pk_max + dot2-accumulate.
// dl-sorted order => if edge1's dl == curn then edge0's dl == curn too.
#define PPROC(X0, Y0, X1, Y1, AA)                                                 \
        {                                                                         \
            const int dl1_ = ((unsigned)(Y1)) >> 16;                              \
            if (__builtin_expect(dl1_ == curn, 1)) {                              \
                const unsigned wsp_ = __builtin_amdgcn_perm((unsigned)(X1), (unsigned)(X0), 0x05040100u); \
                const unsigned wxp_ = __builtin_amdgcn_perm((unsigned)(X1), (unsigned)(X0), 0x07060302u); \
                const unsigned wfp_ = __builtin_amdgcn_perm((unsigned)(Y1), (unsigned)(Y0), 0x05040100u); \
                h2v z_ = ash2(wfp_) * b1f2;                                       \
                z_ = ash2(wxp_) * w1t2 + z_;                                      \
                z_ = ash2(wsp_) * w1r2 + z_;                                      \
                z_ = __builtin_elementwise_max(z_, zero2);                        \
                AA = __builtin_amdgcn_fdot2(z_, one2, AA, false);                 \
            } else {                                                              \
                SPROC(X0, Y0, AA)                                                 \
                SPROC(X1, Y1, AA)                                                 \
            }                                                                     \
        }

        // align to even record index so int4 loads are 16B-aligned
        if (e < eend && (e & 1)) {
            int2 qq = rec2[e];
            SPROC(qq.x, qq.y, a0)
            ++e;
        }
        const int4* rp = (const int4*)(rec2 + e);
        bool have = (e + 8 <= eend);
        int4 q0, q1, q2, q3;
        if (have) { q0 = rp[0]; q1 = rp[1]; q2 = rp[2]; q3 = rp[3]; }
        while (have) {
            int4 n0, n1, n2, n3;
            const bool nxt = (e + 16 <= eend);
            if (nxt) { n0 = rp[4]; n1 = rp[5]; n2 = rp[6]; n3 = rp[7]; }
            PPROC(q0.x, q0.y, q0.z, q0.w, a0)
            PPROC(q1.x, q1.y, q1.z, q1.w, a1)
            PPROC(q2.x, q2.y, q2.z, q2.w, a2)
            PPROC(q3.x, q3.y, q3.z, q3.w, a3)
            e += 8; rp += 4;
            have = nxt;
            if (nxt) { q0 = n0; q1 = n1; q2 = n2; q3 = n3; }
        }
        for (; e < eend; ++e) {
            int2 qq = rec2[e];
            SPROC(qq.x, qq.y, a0)
        }
        FLUSHA();
#undef PPROC
#undef SPROC
#undef FLUSHA
    }
    __syncthreads();

    const int m16 = tid & 15;
    const int quad = (tid & 63) >> 4;
    f32x4 acc[4];
    #pragma unroll
    for (int c_ = 0; c_ < 4; ++c_) acc[c_] = (f32x4){0.f, 0.f, 0.f, 0.f};

    const float2 sm = sxl[wv * 16 + m16];

    #pragma unroll
    for (int kt = 0; kt < 4; ++kt) {
        const int kk = kt * 32;
        half8 a0;
        if (kt < 2) {
            a0 = *(const half8*)&aggh[(wv * 16 + m16) * AP + kk + quad * 8];
        } else {
            const int fk0 = (kt - 2) * 32 + quad * 8;
            #pragma unroll
            for (int j = 0; j < 8; ++j) {
                const float wr = W1_rel[fk0 + j], wt = W1_root[fk0 + j], bb = b1[fk0 + j];
                a0[j] = (_Float16)fmaxf(0.f, fmaf(sm.x, wr, fmaf(sm.y, wt, bb)));
            }
        }
        #pragma unroll
        for (int ct = 0; ct < 4; ++ct) {
            const half8 bfrag = *(const half8*)&Bt[(ct * 16 + m16) * BPITCH + kk + quad * 8];
            acc[ct] = __builtin_amdgcn_mfma_f32_16x16x32_f16(a0, bfrag, acc[ct], 0, 0, 0);
        }
    }

    float b2c[4], w3rc[4], w3tc[4];
    #pragma unroll
    for (int ct = 0; ct < 4; ++ct) {
        const int col = ct * 16 + m16;
        b2c[ct] = b2[col]; w3rc[ct] = W3_rel[col]; w3tc[ct] = W3_root[col];
    }
    float pv[4] = {0.f, 0.f, 0.f, 0.f}, rv[4] = {0.f, 0.f, 0.f, 0.f};
    #pragma unroll
    for (int ct = 0; ct < 4; ++ct) {
        #pragma unroll
        for (int reg = 0; reg < 4; ++reg) {
            const float h2_ = fmaxf(0.f, acc[ct][reg] + b2c[ct]);
            pv[reg] = fmaf(h2_, w3rc[ct], pv[reg]);
            rv[reg] = fmaf(h2_, w3tc[ct], rv[reg]);
        }
    }
    #pragma unroll
    for (int reg = 0; reg < 4; ++reg) {
        #pragma unroll
        for (int msk = 1; msk < 16; msk <<= 1) {
            pv[reg] += __shfl_xor(pv[reg], msk, 64);
            rv[reg] += __shfl_xor(rv[reg], msk, 64);
        }
    }
    if (m16 == 0) {
        #pragma unroll
        for (int reg = 0; reg < 4; ++reg) {
            const int gi = gi0 + wv * 16 + quad * 4 + reg;
            if (gi < NN) { p[gi] = pv[reg]; r[gi] = rv[reg]; }
        }
    }
}

// -------- bucketed output (unsorted rec): out = seg_sum(w * p[src]) + r + b3 --------
__global__ __launch_bounds__(512) void k_out(const int* __restrict__ gcur,
                                             const int2* __restrict__ rec,
                                             const float* __restrict__ pp,
                                             const float* __restrict__ rr,
                                             const float* __restrict__ b3,
                                             float* __restrict__ out) {
    __shared__ float loc[NPB];
    if (threadIdx.x < NPB) loc[threadIdx.x] = 0.f;
    __syncthreads();
    const int b = blockIdx.x;
    const int beg = b * CAP, cnt = gcur[b] - beg;
    for (int t = threadIdx.x; t < cnt; t += 512) {
        int2 rc = rec[beg + t];
        atomicAdd(&loc[rc.x >> 17], __int_as_float(rc.y) * pp[rc.x & SRCM]);
    }
    __syncthreads();
    int i = b * NPB + threadIdx.x;
    if (threadIdx.x < NPB && i < NN) out[i] = loc[threadIdx.x] + rr[i] + b3[0];
}

extern "C" void kernel_launch(void* const* d_in, const int* in_sizes, int n_in,
                              void* d_out, int out_size, void* d_ws, size_t ws_size,
                              hipStream_t stream) {
    const float* x       = (const float*)d_in[0];
    const int*   ei      = (const int*)  d_in[1];
    const float* ew      = (const float*)d_in[2];
    const float* W1_rel  = (const float*)d_in[3];
    const float* b1      = (const float*)d_in[4];
    const float* W1_root = (const float*)d_in[5];
    const float* W2_rel  = (const float*)d_in[6];
    const float* b2      = (const float*)d_in[7];
    const float* W2_root = (const float*)d_in[8];
    const float* W3_rel  = (const float*)d_in[9];
    const float* b3      = (const float*)d_in[10];
    const float* W3_root = (const float*)d_in[11];

    const int* src = ei;
    const int* dst = ei + NE;

    // workspace layout (~60 MB of the ~268 MB workspace)
    const size_t REC_SLOTS = (size_t)NB * CAP;            // 3.6M slots
    int2*   rec   = (int2*)d_ws;                          // 28.8 MB
    float2* sx    = (float2*)(rec + REC_SLOTS);
    float*  p     = (float*)(sx + NN);
    float*  r     = p + NN;
    int*    nbase = (int*)(r + NN);
    int*    nend  = nbase + NN;
    int*    gcur  = nend + NN;
    char*   tail  = (char*)(gcur + NB);
    size_t  off   = ((size_t)(tail - (char*)d_ws) + 15) & ~(size_t)15;  // 16B align for int4 loads
    int2*   rec2  = (int2*)((char*)d_ws + off);           // 28.8 MB

    k_init<<<1, 512, 0, stream>>>(gcur);
    k_scatter<<<NCH, 256, 0, stream>>>(src, dst, ew, gcur, rec);
    k_s1<<<NB, 512, 0, stream>>>(gcur, rec, x, sx);
    k_sort2<<<NB, 512, 0, stream>>>(gcur, rec, sx, rec2, nbase, nend);
    k_mega<<<NMW, 512, 0, stream>>>(nbase, nend, rec2, sx,
                                    W1_rel, W1_root, b1,
                                    W2_rel, b2, W2_root,
                                    W3_rel, W3_root, p, r);
    k_out<<<NB, 512, 0, stream>>>(gcur, rec, p, r, b3, (float*)d_out);
}

// Round 2
// 290.628 us; speedup vs baseline: 1.1137x; 1.0087x over previous
//
#include <hip/hip_runtime.h>

#define NN 100000
#define NE 3200000
#define HID 64
#define NPB 256                         // nodes per bucket (dl = dst & 255)
#define NB  ((NN + NPB - 1) / NPB)      // 391 buckets
#define NNP (NB * NPB)                  // 100096 padded node slots
#define CAP 9216                        // raw bucket capacity: mean 8192, +11 sigma
#define CAP2 10240                      // padded bucket capacity: mean ~9101, +11 sigma
#define MNP 128                         // nodes per k_mega window
#define NMW ((NN + MNP - 1) / MNP)      // 782 mega windows
#define CHUNK 4096                      // edges per scatter workgroup
#define NCH ((NE + CHUNK - 1) / CHUNK)  // 782 chunks
#define AP 72                           // f16 agg row pitch in halfs (144 B)
#define BPITCH 136                      // f16 Bt row pitch in halfs (272 B)
#define SRCM 0x1FFFF                    // src mask (17 bits; NN < 2^17)

typedef _Float16 half8 __attribute__((ext_vector_type(8)));
typedef _Float16 h2v   __attribute__((ext_vector_type(2)));
typedef float f32x4 __attribute__((ext_vector_type(4)));

__device__ __forceinline__ unsigned short f2hb(float v) {
    _Float16 h = (_Float16)v;
    unsigned short s;
    __builtin_memcpy(&s, &h, 2);
    return s;
}
__device__ __forceinline__ h2v ash2(unsigned int u) {
    h2v r;
    __builtin_memcpy(&r, &u, 4);
    return r;
}

// -------- init fixed-capacity bucket cursors --------
__global__ __launch_bounds__(512) void k_init(int* __restrict__ gcur) {
    const int t = threadIdx.x;
    if (t < NB) gcur[t] = t * CAP;
}

// -------- scatter: in-LDS counting sort -> bucket-grouped coalesced emission ----
// LDS = 52.3 KB -> 3 blocks/CU (was 54.7 -> 2/CU). shfl-based scan, no sc[512].
__global__ __launch_bounds__(256) void k_scatter(const int* __restrict__ src,
                                                 const int* __restrict__ dst,
                                                 const float* __restrict__ ew,
                                                 int* __restrict__ gcur,
                                                 int2* __restrict__ rec,
                                                 unsigned char* __restrict__ dlb) {
    __shared__ int2 lrec[CHUNK];              // 32 KB
    __shared__ unsigned short lb[CHUNK];      // 8 KB  (bucket id per record)
    __shared__ unsigned short sidx[CHUNK];    // 8 KB  (sorted-order -> record idx)
    __shared__ int cnt[NB];                   // counts, then cursor (=excl)
    __shared__ int bme[NB];                   // base - excl
    __shared__ int wt8[8];                    // wave scan partials
    const int tid = threadIdx.x;
    const int lane = tid & 63, wvx = tid >> 6;   // 4 waves
    for (int j = tid; j < NB; j += 256) cnt[j] = 0;
    __syncthreads();
    const long long b0 = (long long)blockIdx.x * CHUNK;
    const int valid = (int)min((long long)CHUNK, (long long)NE - b0);
    #pragma unroll
    for (int k = 0; k < CHUNK / 256; ++k) {
        int idx = k * 256 + tid;
        if (idx < valid) {
            long long e = b0 + idx;
            int d = dst[e];
            int b = d >> 8;
            lrec[idx] = make_int2(src[e] | ((d & 255) << 17), __float_as_int(ew[e]));
            lb[idx] = (unsigned short)b;
            atomicAdd(&cnt[b], 1);
        }
    }
    __syncthreads();
    // exclusive scan of 512 slots (NB=391 live) via per-wave shfl scans
    int v0 = (tid < NB) ? cnt[tid] : 0;
    int v1 = (tid + 256 < NB) ? cnt[tid + 256] : 0;
    int i0 = v0, i1 = v1;
    #pragma unroll
    for (int off = 1; off < 64; off <<= 1) {
        int t0 = __shfl_up(i0, off, 64);
        int t1 = __shfl_up(i1, off, 64);
        if (lane >= off) { i0 += t0; i1 += t1; }
    }
    if (lane == 63) { wt8[wvx] = i0; wt8[4 + wvx] = i1; }
    __syncthreads();
    int off0 = 0, off1 = 0;
    #pragma unroll
    for (int j = 0; j < 8; ++j) {
        int wt = wt8[j];
        if (j < wvx) off0 += wt;
        if (j < 4 + wvx) off1 += wt;
    }
    const int excl0 = off0 + i0 - v0;
    const int excl1 = off1 + i1 - v1;
    // global reservation; bme = base - excl; cursor cnt[slot] = excl
    if (tid < NB) {
        int bb = v0 ? atomicAdd(&gcur[tid], v0) : 0;
        bme[tid] = bb - excl0;
        cnt[tid] = excl0;
    }
    if (tid + 256 < NB) {
        int bb = v1 ? atomicAdd(&gcur[tid + 256], v1) : 0;
        bme[tid + 256] = bb - excl1;
        cnt[tid + 256] = excl1;
    }
    __syncthreads();
    // placement: sorted position per record
    #pragma unroll
    for (int k = 0; k < CHUNK / 256; ++k) {
        int idx = k * 256 + tid;
        if (idx < valid) {
            int sp = atomicAdd(&cnt[lb[idx]], 1);
            sidx[sp] = (unsigned short)idx;
        }
    }
    __syncthreads();
    // emission in bucket order: consecutive lanes -> consecutive addresses per run
    #pragma unroll
    for (int k = 0; k < CHUNK / 256; ++k) {
        int sp = k * 256 + tid;
        if (sp < valid) {
            int idx = sidx[sp];
            int b = lb[idx];
            int2 rc = lrec[idx];
            int go = bme[b] + sp;
            rec[go] = rc;
            dlb[go] = (unsigned char)((rc.x >> 17) & 255);
        }
    }
}

// -------- bucketed s1: sx[i] = (s1[i], x[i]) --------
__global__ __launch_bounds__(512) void k_s1(const int* __restrict__ gcur,
                                            const int2* __restrict__ rec,
                                            const float* __restrict__ x,
                                            float2* __restrict__ sx) {
    __shared__ float loc[NPB];
    if (threadIdx.x < NPB) loc[threadIdx.x] = 0.f;
    __syncthreads();
    const int b = blockIdx.x;
    const int beg = b * CAP, cnt = gcur[b] - beg;
    for (int t = threadIdx.x; t < cnt; t += 512) {
        int2 rc = rec[beg + t];
        atomicAdd(&loc[rc.x >> 17], __int_as_float(rc.y) * x[rc.x & SRCM]);
    }
    __syncthreads();
    int i = b * NPB + threadIdx.x;
    if (threadIdx.x < NPB && i < NN) sx[i] = make_float2(loc[threadIdx.x], x[i]);
}

// -------- sort2: dlb hist -> padded scan -> pair-transposed rec2 emit --------
// rec2 layout: per pair of slots (16B): {ws0|ws1<<16, wx0|wx1<<16, wf0|wf1<<16, pad}
// each node's run padded with zeros to a multiple of 8 slots (zeros contribute 0).
__global__ __launch_bounds__(512) void k_sort2(const int* __restrict__ gcur,
                                               const int2* __restrict__ rec,
                                               const unsigned char* __restrict__ dlb,
                                               const float2* __restrict__ sx,
                                               unsigned short* __restrict__ rec2h,
                                               int* __restrict__ noff,
                                               unsigned char* __restrict__ ngrp) {
    __shared__ int hist[NPB];
    __shared__ int exclp[NPB];
    __shared__ int cur[NPB];
    __shared__ int wt4[4];
    const int tid = threadIdx.x;
    const int lane = tid & 63, wvx = tid >> 6;
    if (tid < NPB) hist[tid] = 0;
    __syncthreads();
    const int b = blockIdx.x;
    const int beg = b * CAP, cnt = gcur[b] - beg;
    for (int t = tid; t < cnt; t += 512)
        atomicAdd(&hist[dlb[beg + t]], 1);
    __syncthreads();
    // padded exclusive scan over 256 dl slots (waves 0..3)
    int pc = 0;
    if (tid < NPB) pc = (hist[tid] + 7) & ~7;
    int incl = pc;
    #pragma unroll
    for (int off = 1; off < 64; off <<= 1) {
        int tt = __shfl_up(incl, off, 64);
        if (lane >= off) incl += tt;
    }
    if (tid < NPB && lane == 63) wt4[wvx] = incl;
    __syncthreads();
    if (tid < NPB) {
        int offs = 0;
        #pragma unroll
        for (int j = 0; j < 4; ++j)
            if (j < wvx) offs += wt4[j];
        int e0 = offs + incl - pc;
        exclp[tid] = e0;
        cur[tid] = e0;
        const int node = b * NPB + tid;
        noff[node] = b * CAP2 + e0;
        ngrp[node] = (unsigned char)(pc >> 3);
    }
    __syncthreads();
    // zero-pad slots [deg, roundup8(deg)) per dl (independent of pass2)
    if (tid < NPB) {
        const int d = hist[tid];
        const int pe = (d + 7) & ~7;
        const size_t gb = (size_t)b * CAP2 + exclp[tid];
        for (int j = d; j < pe; ++j) {
            size_t gs = gb + j;
            size_t hb = (gs >> 1) * 8 + (gs & 1);
            rec2h[hb] = 0; rec2h[hb + 2] = 0; rec2h[hb + 4] = 0;
        }
    }
    // pass2: stream rec, gather sx, pair-transposed scatter
    for (int t = tid; t < cnt; t += 512) {
        int2 rc = rec[beg + t];
        const int s = rc.x & SRCM;
        const int dl = (rc.x >> 17) & 255;
        const float w = __int_as_float(rc.y);
        const float2 v = sx[s];
        int pos = atomicAdd(&cur[dl], 1);
        size_t gs = (size_t)b * CAP2 + pos;
        size_t hb = (gs >> 1) * 8 + (gs & 1);
        rec2h[hb]     = f2hb(w * v.x);
        rec2h[hb + 2] = f2hb(w * v.y);
        rec2h[hb + 4] = f2hb(w);
    }
}

// -------- mega: branchless pair-transposed streaming + MFMA --------
__global__ __launch_bounds__(512) void k_mega(
        const int* __restrict__ noff, const unsigned char* __restrict__ ngrp,
        const char* __restrict__ rec2b, const float2* __restrict__ sx,
        const float* __restrict__ W1_rel, const float* __restrict__ W1_root,
        const float* __restrict__ b1,
        const float* __restrict__ W2_rel, const float* __restrict__ b2,
        const float* __restrict__ W2_root,
        const float* __restrict__ W3_rel, const float* __restrict__ W3_root,
        float* __restrict__ p, float* __restrict__ r) {
    __shared__ _Float16 aggh[MNP * AP];       // 18432 B
    __shared__ _Float16 Bt[HID * BPITCH];     // 17408 B
    __shared__ float2 sxl[MNP];               // 1024 B -> 36.9 KB
    const int tid = threadIdx.x;
    const int f = tid & 63;
    const int wv = tid >> 6;                  // 0..7
    const int gi0 = blockIdx.x * MNP;

    for (int j = tid; j < MNP * AP / 2; j += 512) ((int*)aggh)[j] = 0;
    for (int idx = tid; idx < HID * HID; idx += 512) {
        int k = idx >> 6, n = idx & 63;
        Bt[n * BPITCH + k]       = (_Float16)W2_rel[idx];
        Bt[n * BPITCH + HID + k] = (_Float16)W2_root[idx];
    }
    if (tid < MNP) {
        int gi = gi0 + tid;
        sxl[tid] = (gi < NN) ? sx[gi] : make_float2(0.f, 0.f);
    }
    const float w1rf = W1_rel[f], w1tf = W1_root[f], b1ff = b1[f];
    __syncthreads();

    {
        const int first = gi0 + wv * 16;
        // wave-uniform metadata (scalarize)
        int soff = __builtin_amdgcn_readfirstlane(noff[first]);
        const int4 gvv = *(const int4*)(ngrp + first);
        unsigned ua = __builtin_amdgcn_readfirstlane((unsigned)gvv.x);
        unsigned ub = __builtin_amdgcn_readfirstlane((unsigned)gvv.y);
        unsigned uc = __builtin_amdgcn_readfirstlane((unsigned)gvv.z);
        unsigned ud = __builtin_amdgcn_readfirstlane((unsigned)gvv.w);
        unsigned long long clo = (unsigned long long)ua | ((unsigned long long)ub << 32);
        unsigned long long chi = (unsigned long long)uc | ((unsigned long long)ud << 32);
        #define BSUM(u) (((u) & 255u) + (((u) >> 8) & 255u) + (((u) >> 16) & 255u) + ((u) >> 24))
        const int tg = (int)(BSUM(ua) + BSUM(ub) + BSUM(uc) + BSUM(ud));
        #undef BSUM

        const h2v w1r2 = {(_Float16)w1rf, (_Float16)w1rf};
        const h2v w1t2 = {(_Float16)w1tf, (_Float16)w1tf};
        const h2v b1f2 = {(_Float16)b1ff, (_Float16)b1ff};
        const h2v one2 = {(_Float16)1.f, (_Float16)1.f};
        const h2v zero2 = {(_Float16)0.f, (_Float16)0.f};

        float a0 = 0.f, a1 = 0.f, a2 = 0.f, a3 = 0.f;
        int nrow = wv * 16;
        const int rowend = nrow + 16;
        // consume first count, skip zero-degree leading nodes
        int grem = (int)(clo & 255); clo = (clo >> 8) | (chi << 56); chi >>= 8;
        while (grem == 0 && nrow + 1 < rowend) {
            ++nrow; grem = (int)(clo & 255);
            clo = (clo >> 8) | (chi << 56); chi >>= 8;
        }

        const int4* rp = (const int4*)rec2b + (soff >> 1);
        int4 A0, A1, A2, A3, B0, B1, B2, B3;
        if (tg >= 1) { A0 = rp[0]; A1 = rp[1]; A2 = rp[2]; A3 = rp[3]; }
        if (tg >= 2) { B0 = rp[4]; B1 = rp[5]; B2 = rp[6]; B3 = rp[7]; }
        rp += 8;

// branchless pair: 5 VALU for 2 edges across all 64 features
#define PP(Q, AA) {                                          \
        h2v z_ = ash2((unsigned)(Q).z) * b1f2;               \
        z_ = ash2((unsigned)(Q).y) * w1t2 + z_;              \
        z_ = ash2((unsigned)(Q).x) * w1r2 + z_;              \
        z_ = __builtin_elementwise_max(z_, zero2);           \
        AA = __builtin_amdgcn_fdot2(z_, one2, AA, false); }

#define BNDRY() {                                                        \
        if (--grem == 0) {                                               \
            aggh[nrow * AP + f] = (_Float16)((a0 + a1) + (a2 + a3));     \
            a0 = a1 = a2 = a3 = 0.f;                                     \
            ++nrow; grem = (int)(clo & 255);                             \
            clo = (clo >> 8) | (chi << 56); chi >>= 8;                   \
            while (grem == 0 && nrow + 1 < rowend) {                     \
                ++nrow; grem = (int)(clo & 255);                         \
                clo = (clo >> 8) | (chi << 56); chi >>= 8;               \
            }                                                            \
        } }

        int t = 0;
        while (t + 2 <= tg) {
            PP(A0, a0) PP(A1, a1) PP(A2, a2) PP(A3, a3)
            A0 = rp[0]; A1 = rp[1]; A2 = rp[2]; A3 = rp[3]; rp += 4;
            BNDRY(); ++t;
            PP(B0, a0) PP(B1, a1) PP(B2, a2) PP(B3, a3)
            B0 = rp[0]; B1 = rp[1]; B2 = rp[2]; B3 = rp[3]; rp += 4;
            BNDRY(); ++t;
        }
        if (t < tg) {
            PP(A0, a0) PP(A1, a1) PP(A2, a2) PP(A3, a3)
            BNDRY();
        }
#undef PP
#undef BNDRY
    }
    __syncthreads();

    const int m16 = tid & 15;
    const int quad = (tid & 63) >> 4;
    f32x4 acc[4];
    #pragma unroll
    for (int c_ = 0; c_ < 4; ++c_) acc[c_] = (f32x4){0.f, 0.f, 0.f, 0.f};

    const float2 sm = sxl[wv * 16 + m16];

    #pragma unroll
    for (int kt = 0; kt < 4; ++kt) {
        const int kk = kt * 32;
        half8 af;
        if (kt < 2) {
            af = *(const half8*)&aggh[(wv * 16 + m16) * AP + kk + quad * 8];
        } else {
            const int fk0 = (kt - 2) * 32 + quad * 8;
            #pragma unroll
            for (int j = 0; j < 8; ++j) {
                const float wr = W1_rel[fk0 + j], wt = W1_root[fk0 + j], bb = b1[fk0 + j];
                af[j] = (_Float16)fmaxf(0.f, fmaf(sm.x, wr, fmaf(sm.y, wt, bb)));
            }
        }
        #pragma unroll
        for (int ct = 0; ct < 4; ++ct) {
            const half8 bfrag = *(const half8*)&Bt[(ct * 16 + m16) * BPITCH + kk + quad * 8];
            acc[ct] = __builtin_amdgcn_mfma_f32_16x16x32_f16(af, bfrag, acc[ct], 0, 0, 0);
        }
    }

    float b2c[4], w3rc[4], w3tc[4];
    #pragma unroll
    for (int ct = 0; ct < 4; ++ct) {
        const int col = ct * 16 + m16;
        b2c[ct] = b2[col]; w3rc[ct] = W3_rel[col]; w3tc[ct] = W3_root[col];
    }
    float pv[4] = {0.f, 0.f, 0.f, 0.f}, rv[4] = {0.f, 0.f, 0.f, 0.f};
    #pragma unroll
    for (int ct = 0; ct < 4; ++ct) {
        #pragma unroll
        for (int reg = 0; reg < 4; ++reg) {
            const float h2_ = fmaxf(0.f, acc[ct][reg] + b2c[ct]);
            pv[reg] = fmaf(h2_, w3rc[ct], pv[reg]);
            rv[reg] = fmaf(h2_, w3tc[ct], rv[reg]);
        }
    }
    #pragma unroll
    for (int reg = 0; reg < 4; ++reg) {
        #pragma unroll
        for (int msk = 1; msk < 16; msk <<= 1) {
            pv[reg] += __shfl_xor(pv[reg], msk, 64);
            rv[reg] += __shfl_xor(rv[reg], msk, 64);
        }
    }
    if (m16 == 0) {
        #pragma unroll
        for (int reg = 0; reg < 4; ++reg) {
            const int gi = gi0 + wv * 16 + quad * 4 + reg;
            if (gi < NN) { p[gi] = pv[reg]; r[gi] = rv[reg]; }
        }
    }
}

// -------- bucketed output (unsorted rec): out = seg_sum(w * p[src]) + r + b3 --------
__global__ __launch_bounds__(512) void k_out(const int* __restrict__ gcur,
                                             const int2* __restrict__ rec,
                                             const float* __restrict__ pp,
                                             const float* __restrict__ rr,
                                             const float* __restrict__ b3,
                                             float* __restrict__ out) {
    __shared__ float loc[NPB];
    if (threadIdx.x < NPB) loc[threadIdx.x] = 0.f;
    __syncthreads();
    const int b = blockIdx.x;
    const int beg = b * CAP, cnt = gcur[b] - beg;
    for (int t = threadIdx.x; t < cnt; t += 512) {
        int2 rc = rec[beg + t];
        atomicAdd(&loc[rc.x >> 17], __int_as_float(rc.y) * pp[rc.x & SRCM]);
    }
    __syncthreads();
    int i = b * NPB + threadIdx.x;
    if (threadIdx.x < NPB && i < NN) out[i] = loc[threadIdx.x] + rr[i] + b3[0];
}

extern "C" void kernel_launch(void* const* d_in, const int* in_sizes, int n_in,
                              void* d_out, int out_size, void* d_ws, size_t ws_size,
                              hipStream_t stream) {
    const float* x       = (const float*)d_in[0];
    const int*   ei      = (const int*)  d_in[1];
    const float* ew      = (const float*)d_in[2];
    const float* W1_rel  = (const float*)d_in[3];
    const float* b1      = (const float*)d_in[4];
    const float* W1_root = (const float*)d_in[5];
    const float* W2_rel  = (const float*)d_in[6];
    const float* b2      = (const float*)d_in[7];
    const float* W2_root = (const float*)d_in[8];
    const float* W3_rel  = (const float*)d_in[9];
    const float* b3      = (const float*)d_in[10];
    const float* W3_root = (const float*)d_in[11];

    const int* src = ei;
    const int* dst = ei + NE;

    // workspace layout (~67 MB of the ~268 MB workspace), all chunks 16B-aligned
    const size_t REC_SLOTS = (size_t)NB * CAP;            // 3.60M slots, 28.8 MB
    int2*          rec   = (int2*)d_ws;
    float2*        sx    = (float2*)(rec + REC_SLOTS);    // 800,768 B
    float*         p     = (float*)(sx + NN);             // 400,000 B
    float*         r     = p + NN;                        // 400,000 B
    int*           noff  = (int*)(r + NN);                // NNP*4 = 400,384 B
    unsigned char* ngrp  = (unsigned char*)(noff + NNP);  // 100,096 B
    int*           gcur  = (int*)(ngrp + NNP);            // NB*4
    unsigned char* dlb   = (unsigned char*)(gcur + NB);   // NB*CAP = 3.6 MB
    char*          tail  = (char*)(dlb + REC_SLOTS);
    size_t         off   = ((size_t)(tail - (char*)d_ws) + 15) & ~(size_t)15;
    char*          rec2  = (char*)d_ws + off;             // NB*CAP2*8 + 256 slack = 32.0 MB

    k_init<<<1, 512, 0, stream>>>(gcur);
    k_scatter<<<NCH, 256, 0, stream>>>(src, dst, ew, gcur, rec, dlb);
    k_s1<<<NB, 512, 0, stream>>>(gcur, rec, x, sx);
    k_sort2<<<NB, 512, 0, stream>>>(gcur, rec, dlb, sx,
                                    (unsigned short*)rec2, noff, ngrp);
    k_mega<<<NMW, 512, 0, stream>>>(noff, ngrp, rec2, sx,
                                    W1_rel, W1_root, b1,
                                    W2_rel, b2, W2_root,
                                    W3_rel, W3_root, p, r);
    k_out<<<NB, 512, 0, stream>>>(gcur, rec, p, r, b3, (float*)d_out);
}